// Round 2
// baseline (38986.816 us; speedup 1.0000x reference)
//
#include <hip/hip_runtime.h>
#include <cmath>

namespace {

constexpr int kB = 64;     // batch
constexpr int kT = 512;    // time steps
constexpr int kI = 256;    // input size
constexpr int kH = 1024;   // hidden
constexpr int kNC = 1000;  // classes
constexpr int kChunk = 128;
constexpr int kPad = 132;  // LDS row stride in dwords (128 + 4 pad -> bank-friendly)

__device__ __forceinline__ float sigmoidf_(float x) {
  return 1.0f / (1.0f + expf(-x));
}

__device__ __forceinline__ float dot4_(float4 a, float4 b) {
  return a.x * b.x + a.y * b.y + a.z * b.z + a.w * b.w;
}

// One LSTM cell step for 4 hidden units (16 gate rows) x 64 batches.
// Input vector per batch = [inA (lenA) | inB (kH)]; weights Wa:[4H][lenA], Wb:[4H][kH].
// Gate rows for unit u, gate g live at global row g*kH + u0 + u.
// Thread map: rp = tid&7 (row-pair), bp = tid>>3 (batch-pair) -> lanes with same bp
// broadcast-read in_lds, lanes with same rp broadcast-read w_lds.
__device__ void lstm_phase(
    int tid, int u0,
    const float* __restrict__ inA, int strideA, int lenA,
    const float* __restrict__ inB,
    const float* __restrict__ Wa,
    const float* __restrict__ Wb,
    const float* __restrict__ bias,
    float* __restrict__ c_st,
    float* __restrict__ h_out,
    float (*in_lds)[kPad], float (*w_lds)[kPad]) {
  const int rp = tid & 7;
  const int bp = tid >> 3;          // 0..31 over whole block
  const int lr0 = 2 * rp;           // local rows (lr = u*4 + g)
  const int lr1 = lr0 + 1;
  const int row0 = (lr0 & 3) * kH + u0 + (lr0 >> 2);
  const int row1 = (lr1 & 3) * kH + u0 + (lr1 >> 2);
  float acc00 = bias[row0], acc01 = acc00;  // acc[row][batch]
  float acc10 = bias[row1], acc11 = acc10;

  const int nA = lenA / kChunk;
  const int nTot = nA + kH / kChunk;

  // staging maps
  const int sb = tid >> 2;  // batch row for input staging
  const int sc = tid & 3;
  const int wl = tid >> 4;  // weight row for weight staging
  const int wt = tid & 15;
  const int wrow = (wl & 3) * kH + u0 + (wl >> 2);

  for (int c = 0; c < nTot; ++c) {
    const int kbase = c * kChunk;
    {  // stage inputs: 64 x 128 floats
      const float* src = (c < nA) ? (inA + (size_t)sb * strideA + kbase)
                                  : (inB + (size_t)sb * kH + (kbase - lenA));
#pragma unroll
      for (int j = 0; j < 8; ++j) {
        const int kk = (sc + j * 4) * 4;
        *reinterpret_cast<float4*>(&in_lds[sb][kk]) =
            *reinterpret_cast<const float4*>(src + kk);
      }
    }
    {  // stage weights: 16 x 128 floats
      const float* wsrc = (c < nA) ? (Wa + (size_t)wrow * lenA + kbase)
                                   : (Wb + (size_t)wrow * kH + (kbase - lenA));
#pragma unroll
      for (int j = 0; j < 2; ++j) {
        const int kk = wt * 8 + j * 4;
        *reinterpret_cast<float4*>(&w_lds[wl][kk]) =
            *reinterpret_cast<const float4*>(wsrc + kk);
      }
    }
    __syncthreads();
#pragma unroll
    for (int k = 0; k < kChunk; k += 8) {
      float4 wa0 = *reinterpret_cast<const float4*>(&w_lds[lr0][k]);
      float4 wa1 = *reinterpret_cast<const float4*>(&w_lds[lr0][k + 4]);
      float4 wb0 = *reinterpret_cast<const float4*>(&w_lds[lr1][k]);
      float4 wb1 = *reinterpret_cast<const float4*>(&w_lds[lr1][k + 4]);
      float4 ia0 = *reinterpret_cast<const float4*>(&in_lds[2 * bp][k]);
      float4 ia1 = *reinterpret_cast<const float4*>(&in_lds[2 * bp][k + 4]);
      float4 ib0 = *reinterpret_cast<const float4*>(&in_lds[2 * bp + 1][k]);
      float4 ib1 = *reinterpret_cast<const float4*>(&in_lds[2 * bp + 1][k + 4]);
      acc00 += dot4_(wa0, ia0) + dot4_(wa1, ia1);
      acc01 += dot4_(wa0, ib0) + dot4_(wa1, ib1);
      acc10 += dot4_(wb0, ia0) + dot4_(wb1, ia1);
      acc11 += dot4_(wb0, ib0) + dot4_(wb1, ib1);
    }
    __syncthreads();
  }

  // Epilogue: rp even holds (i, f) rows; partner rp odd holds (g, o) rows of same unit.
  const bool isif = (rp & 1) == 0;
  float v00, v01, v10, v11;
  if (isif) {
    v00 = sigmoidf_(acc00); v01 = sigmoidf_(acc01);  // i
    v10 = sigmoidf_(acc10); v11 = sigmoidf_(acc11);  // f
  } else {
    v00 = tanhf(acc00);     v01 = tanhf(acc01);      // g
    v10 = sigmoidf_(acc10); v11 = sigmoidf_(acc11);  // o
  }
  const float p00 = __shfl_xor(v00, 1);
  const float p01 = __shfl_xor(v01, 1);
  const float p10 = __shfl_xor(v10, 1);
  const float p11 = __shfl_xor(v11, 1);
  if (isif) {
    const int ug = u0 + (rp >> 1);
    const int ba = 2 * bp, bb = 2 * bp + 1;
    float co = c_st[(size_t)ba * kH + ug];
    float cn = v10 * co + v00 * p00;  // f*c + i*g
    c_st[(size_t)ba * kH + ug] = cn;
    h_out[(size_t)ba * kH + ug] = p10 * tanhf(cn);  // o * tanh(c)
    co = c_st[(size_t)bb * kH + ug];
    cn = v11 * co + v01 * p01;
    c_st[(size_t)bb * kH + ug] = cn;
    h_out[(size_t)bb * kH + ug] = p11 * tanhf(cn);
  }
}

// Superstep s: layer A computes t=s (if s<T), layer B computes t=s-1 (if s>=1).
// hA[p] holds hA_t with t&1==p; hB[p] holds hB_t with t&1==p.
__global__ __launch_bounds__(256) void lstm_superstep(
    int s, const float* __restrict__ x,
    const float* __restrict__ Wih0, const float* __restrict__ Whh0,
    const float* __restrict__ b0,
    const float* __restrict__ Wih1, const float* __restrict__ Whh1,
    const float* __restrict__ b1,
    float* __restrict__ st) {
  __shared__ float in_lds[kB][kPad];
  __shared__ float w_lds[16][kPad];
  const int tid = threadIdx.x;
  const int u0 = blockIdx.x * 4;

  float* hAbuf[2] = {st, st + kB * kH};
  float* cA = st + 2 * kB * kH;
  float* hBbuf[2] = {st + 3 * kB * kH, st + 4 * kB * kH};
  float* cB = st + 5 * kB * kH;

  if (s < kT) {
    // reads hA_{s-1} = hAbuf[(s+1)&1], writes hA_s = hAbuf[s&1]
    lstm_phase(tid, u0, x + (size_t)s * kI, kT * kI, kI,
               hAbuf[(s + 1) & 1], Wih0, Whh0, b0, cA,
               hAbuf[s & 1], in_lds, w_lds);
  }
  __syncthreads();
  if (s >= 1) {
    // reads hA_{s-1} = hAbuf[(s+1)&1], hB_{s-2} = hBbuf[s&1]; writes hB_{s-1} = hBbuf[(s+1)&1]
    lstm_phase(tid, u0, hAbuf[(s + 1) & 1], kH, kH,
               hBbuf[s & 1], Wih1, Whh1, b1, cB,
               hBbuf[(s + 1) & 1], in_lds, w_lds);
  }
}

__global__ __launch_bounds__(256) void fc_kernel(
    const float* __restrict__ h, const float* __restrict__ Wfc,
    const float* __restrict__ bfc, float* __restrict__ out) {
  __shared__ float in_lds[kB][kPad];
  const int tid = threadIdx.x;
  const int cls = blockIdx.x * 4 + (tid & 3);
  const int b = tid >> 2;
  float acc = bfc[cls];
  for (int c = 0; c < kH / kChunk; ++c) {
    {
      const int sb = tid >> 2, sc = tid & 3;
#pragma unroll
      for (int j = 0; j < 8; ++j) {
        const int kk = (sc + j * 4) * 4;
        *reinterpret_cast<float4*>(&in_lds[sb][kk]) =
            *reinterpret_cast<const float4*>(h + (size_t)sb * kH + c * kChunk + kk);
      }
    }
    __syncthreads();
    const float* wrow = Wfc + (size_t)cls * kH + c * kChunk;
#pragma unroll
    for (int k = 0; k < kChunk; k += 4) {
      float4 w = *reinterpret_cast<const float4*>(wrow + k);
      float4 v = *reinterpret_cast<const float4*>(&in_lds[b][k]);
      acc += dot4_(w, v);
    }
    __syncthreads();
  }
  out[(size_t)b * kNC + cls] = fmaxf(acc, 0.0f);
}

}  // namespace

extern "C" void kernel_launch(void* const* d_in, const int* in_sizes, int n_in,
                              void* d_out, int out_size, void* d_ws, size_t ws_size,
                              hipStream_t stream) {
  const float* x    = (const float*)d_in[0];
  const float* Wih0 = (const float*)d_in[1];
  const float* Whh0 = (const float*)d_in[2];
  const float* b0   = (const float*)d_in[3];
  const float* Wih1 = (const float*)d_in[4];
  const float* Whh1 = (const float*)d_in[5];
  const float* b1   = (const float*)d_in[6];
  const float* Wfc  = (const float*)d_in[7];
  const float* bfc  = (const float*)d_in[8];
  float* out = (float*)d_out;
  float* st = (float*)d_ws;

  // zero states: hA0,hA1,cA,hB0,hB1,cB  (6 * 64*1024 floats = 1.5 MB)
  hipMemsetAsync(st, 0, (size_t)6 * kB * kH * sizeof(float), stream);

  for (int s = 0; s <= kT; ++s) {
    lstm_superstep<<<256, 256, 0, stream>>>(s, x, Wih0, Whh0, b0, Wih1, Whh1,
                                            b1, st);
  }
  // hB_511 lives in hBbuf[511&1] = hBbuf[1]
  fc_kernel<<<kNC / 4, 256, 0, stream>>>(st + (size_t)4 * kB * kH, Wfc, bfc,
                                         out);
}

// Round 3
// 17605.074 us; speedup vs baseline: 2.2145x; 2.2145x over previous
//
#include <hip/hip_runtime.h>
#include <cmath>

typedef _Float16 f16x8 __attribute__((ext_vector_type(8)));
typedef float f32x4 __attribute__((ext_vector_type(4)));

namespace {

constexpr int kB = 64;     // batch
constexpr int kT = 512;    // time steps
constexpr int kI = 256;    // input size
constexpr int kH = 1024;   // hidden
constexpr int kNC = 1000;  // classes
constexpr int kKc = 128;   // K chunk per stage iteration
constexpr int kLP = kKc + 8;  // LDS row pitch in f16 (136 -> 272B, 16B aligned, 2-way banks = free)

__device__ __forceinline__ float sigmoidf_(float x) {
  return 1.0f / (1.0f + expf(-x));
}

__device__ __forceinline__ f16x8 ldh8(const _Float16* p) {
  return *reinterpret_cast<const f16x8*>(p);
}

__device__ __forceinline__ float dot4_(float4 a, float4 b) {
  return a.x * b.x + a.y * b.y + a.z * b.z + a.w * b.w;
}

// One LSTM layer step for 4 hidden units x 64 batches via split-f16 MFMA.
// Gate preact = [Whi+Wlo] @ [inhi+inlo] using 3 products (hh, hl, lh).
// A (weights) rows m = unitIdx*4 + gate -> global gate-row (m&3)*kH + u0 + (m>>2).
// MFMA 16x16x32_f16 frag layout: A: lane l holds A[l&15][(l>>4)*8 + j];
// B: lane l holds B[(l>>4)*8 + j][l&15]; C/D: col=l&15, row=(l>>4)*4+reg (m89).
// => epilogue: lane (l>>4)=q holds gates i,f,g,o of unit u0+q, batch w*16+(l&15),
// in acc[0..3] — fully lane-local cell update.
__device__ void lstm_phase_mfma(
    int tid, int u0, int nChunks, int len0,
    const _Float16* __restrict__ Whi, const _Float16* __restrict__ Wlo,
    const _Float16* __restrict__ in0h, const _Float16* __restrict__ in0l,
    const _Float16* __restrict__ in1h, const _Float16* __restrict__ in1l,
    const float* __restrict__ bias, float* __restrict__ c_st,
    _Float16* __restrict__ houth, _Float16* __restrict__ houtl,
    float* __restrict__ houtf,
    _Float16 (*Ahi)[kLP], _Float16 (*Alo)[kLP]) {
  const int lane = tid & 63;
  const int wave = tid >> 6;
  const int K = nChunks * kKc;

  // weight staging map: 256 threads cover 16 rows x 128 k (8 f16 each)
  const int sr = tid >> 4;
  const int sk = (tid & 15) * 8;
  const int grow = (sr & 3) * kH + u0 + (sr >> 2);
  const _Float16* wsrc_h = Whi + (size_t)grow * K + sk;
  const _Float16* wsrc_l = Wlo + (size_t)grow * K + sk;

  // compute map
  const int kg = (lane >> 4) * 8;
  const int am = lane & 15;           // A row in LDS
  const int b = wave * 16 + (lane & 15);  // global batch for B frag

  f32x4 acc = {0.f, 0.f, 0.f, 0.f};

  // preload W chunk 0 + B frags chunk 0
  f16x8 wrh = ldh8(wsrc_h);
  f16x8 wrl = ldh8(wsrc_l);
  f16x8 bh[4], bl[4];
#pragma unroll
  for (int ks = 0; ks < 4; ++ks) {
    const int gk = ks * 32 + kg;
    const _Float16* ph;
    const _Float16* pl;
    if (gk < len0) {
      ph = in0h + (size_t)b * len0 + gk;
      pl = in0l + (size_t)b * len0 + gk;
    } else {
      ph = in1h + (size_t)b * kH + (gk - len0);
      pl = in1l + (size_t)b * kH + (gk - len0);
    }
    bh[ks] = ldh8(ph);
    bl[ks] = ldh8(pl);
  }

  for (int c = 0; c < nChunks; ++c) {
    __syncthreads();  // previous compute done; LDS free to overwrite
    *reinterpret_cast<f16x8*>(&Ahi[sr][sk]) = wrh;
    *reinterpret_cast<f16x8*>(&Alo[sr][sk]) = wrl;
    if (c + 1 < nChunks) {  // prefetch next W chunk (latency hides under compute)
      wrh = ldh8(wsrc_h + (size_t)(c + 1) * kKc);
      wrl = ldh8(wsrc_l + (size_t)(c + 1) * kKc);
    }
    __syncthreads();  // staged chunk visible
    f16x8 nbh[4], nbl[4];
    if (c + 1 < nChunks) {  // prefetch next B frags
      const int k0n = (c + 1) * kKc;
#pragma unroll
      for (int ks = 0; ks < 4; ++ks) {
        const int gk = k0n + ks * 32 + kg;
        const _Float16* ph;
        const _Float16* pl;
        if (gk < len0) {
          ph = in0h + (size_t)b * len0 + gk;
          pl = in0l + (size_t)b * len0 + gk;
        } else {
          ph = in1h + (size_t)b * kH + (gk - len0);
          pl = in1l + (size_t)b * kH + (gk - len0);
        }
        nbh[ks] = ldh8(ph);
        nbl[ks] = ldh8(pl);
      }
    }
#pragma unroll
    for (int ks = 0; ks < 4; ++ks) {
      const int kk = ks * 32 + kg;
      f16x8 ah = ldh8(&Ahi[am][kk]);
      f16x8 al = ldh8(&Alo[am][kk]);
      acc = __builtin_amdgcn_mfma_f32_16x16x32_f16(ah, bh[ks], acc, 0, 0, 0);
      acc = __builtin_amdgcn_mfma_f32_16x16x32_f16(ah, bl[ks], acc, 0, 0, 0);
      acc = __builtin_amdgcn_mfma_f32_16x16x32_f16(al, bh[ks], acc, 0, 0, 0);
    }
#pragma unroll
    for (int ks = 0; ks < 4; ++ks) {
      bh[ks] = nbh[ks];
      bl[ks] = nbl[ks];
    }
  }

  // epilogue: lane-local cell update
  const int eb = wave * 16 + (lane & 15);
  const int eu = u0 + (lane >> 4);
  const size_t idx = (size_t)eb * kH + eu;
  const float gi = sigmoidf_(acc[0] + bias[eu]);
  const float gf = sigmoidf_(acc[1] + bias[kH + eu]);
  const float gg = tanhf(acc[2] + bias[2 * kH + eu]);
  const float go = sigmoidf_(acc[3] + bias[3 * kH + eu]);
  const float cn = gf * c_st[idx] + gi * gg;
  c_st[idx] = cn;
  const float h = go * tanhf(cn);
  const _Float16 hh = (_Float16)h;
  houth[idx] = hh;
  houtl[idx] = (_Float16)(h - (float)hh);
  if (houtf) houtf[idx] = h;
}

// Superstep s: layer A computes hA[s] (if s<T), layer B computes hB[s-1] (if s>=1).
// hA[t] lives in ping t&1; hB[t] in ping t&1. Cross-launch deps are stream-ordered.
__global__ __launch_bounds__(256) void lstm_step(
    int s,
    const _Float16* __restrict__ WAh, const _Float16* __restrict__ WAl,
    const _Float16* __restrict__ WBh, const _Float16* __restrict__ WBl,
    const _Float16* __restrict__ XSh, const _Float16* __restrict__ XSl,
    _Float16* __restrict__ hA, _Float16* __restrict__ hB,
    const float* __restrict__ b0v, const float* __restrict__ b1v,
    float* __restrict__ cA, float* __restrict__ cB,
    float* __restrict__ h2f) {
  __shared__ _Float16 Ahi[16][kLP];
  __shared__ _Float16 Alo[16][kLP];
  const int tid = threadIdx.x;
  const int u0 = blockIdx.x * 4;
  const int HS = kB * kH;
  const int pPrev = (s + 1) & 1, pCur = s & 1;

  _Float16* hAprevH = hA + (size_t)pPrev * 2 * HS;
  _Float16* hAprevL = hAprevH + HS;
  _Float16* hAcurH = hA + (size_t)pCur * 2 * HS;
  _Float16* hAcurL = hAcurH + HS;
  _Float16* hBprevH = hB + (size_t)pCur * 2 * HS;   // hB[s-2]: (s-2)&1 == s&1
  _Float16* hBprevL = hBprevH + HS;
  _Float16* hBcurH = hB + (size_t)pPrev * 2 * HS;   // hB[s-1]: (s-1)&1 == pPrev
  _Float16* hBcurL = hBcurH + HS;

  if (s < kT) {
    lstm_phase_mfma(tid, u0, (kI + kH) / kKc, kI, WAh, WAl,
                    XSh + (size_t)s * kB * kI, XSl + (size_t)s * kB * kI,
                    hAprevH, hAprevL, b0v, cA, hAcurH, hAcurL, nullptr, Ahi,
                    Alo);
  }
  __syncthreads();
  if (s >= 1) {
    lstm_phase_mfma(tid, u0, (kH + kH) / kKc, kH, WBh, WBl, hAprevH, hAprevL,
                    hBprevH, hBprevL, b1v, cB, hBcurH, hBcurL, h2f, Ahi, Alo);
  }
}

// Split fp32 weights [4096][k0len | k1len] into concatenated f16 hi/lo [4096][K].
__global__ __launch_bounds__(256) void prep_wsplit(
    const float* __restrict__ W0, int k0len, const float* __restrict__ W1,
    int k1len, _Float16* __restrict__ oh, _Float16* __restrict__ ol,
    int total) {
  const int K = k0len + k1len;
  for (int i = blockIdx.x * blockDim.x + threadIdx.x; i < total;
       i += gridDim.x * blockDim.x) {
    const int row = i / K, k = i % K;
    const float v = (k < k0len) ? W0[(size_t)row * k0len + k]
                                : W1[(size_t)row * k1len + (k - k0len)];
    const _Float16 h = (_Float16)v;
    oh[i] = h;
    ol[i] = (_Float16)(v - (float)h);
  }
}

// x [b][t][k] fp32 -> xs hi/lo [t][b][k] f16
__global__ __launch_bounds__(256) void prep_xsplit(
    const float* __restrict__ x, _Float16* __restrict__ oh,
    _Float16* __restrict__ ol) {
  const int total = kT * kB * kI;
  for (int i = blockIdx.x * blockDim.x + threadIdx.x; i < total;
       i += gridDim.x * blockDim.x) {
    const int k = i % kI;
    const int rem = i / kI;
    const int bb = rem % kB;
    const int t = rem / kB;
    const float v = x[((size_t)bb * kT + t) * kI + k];
    const _Float16 h = (_Float16)v;
    oh[i] = h;
    ol[i] = (_Float16)(v - (float)h);
  }
}

__global__ __launch_bounds__(256) void fc_kernel(
    const float* __restrict__ h, const float* __restrict__ Wfc,
    const float* __restrict__ bfc, float* __restrict__ out) {
  __shared__ float in_lds[kB][132];
  const int tid = threadIdx.x;
  const int cls = blockIdx.x * 4 + (tid & 3);
  const int b = tid >> 2;
  float acc = bfc[cls];
  for (int c = 0; c < kH / 128; ++c) {
    {
      const int sb = tid >> 2, sc = tid & 3;
#pragma unroll
      for (int j = 0; j < 8; ++j) {
        const int kk = (sc + j * 4) * 4;
        *reinterpret_cast<float4*>(&in_lds[sb][kk]) =
            *reinterpret_cast<const float4*>(h + (size_t)sb * kH + c * 128 + kk);
      }
    }
    __syncthreads();
    const float* wrow = Wfc + (size_t)cls * kH + c * 128;
#pragma unroll
    for (int k = 0; k < 128; k += 4) {
      float4 w = *reinterpret_cast<const float4*>(wrow + k);
      float4 v = *reinterpret_cast<const float4*>(&in_lds[b][k]);
      acc += dot4_(w, v);
    }
    __syncthreads();
  }
  out[(size_t)b * kNC + cls] = fmaxf(acc, 0.0f);
}

}  // namespace

extern "C" void kernel_launch(void* const* d_in, const int* in_sizes, int n_in,
                              void* d_out, int out_size, void* d_ws, size_t ws_size,
                              hipStream_t stream) {
  const float* x    = (const float*)d_in[0];
  const float* Wih0 = (const float*)d_in[1];
  const float* Whh0 = (const float*)d_in[2];
  const float* b0   = (const float*)d_in[3];
  const float* Wih1 = (const float*)d_in[4];
  const float* Whh1 = (const float*)d_in[5];
  const float* b1   = (const float*)d_in[6];
  const float* Wfc  = (const float*)d_in[7];
  const float* bfc  = (const float*)d_in[8];
  float* out = (float*)d_out;

  char* w = (char*)d_ws;
  size_t off = 0;
  auto a16 = [&](size_t n) {
    _Float16* p = (_Float16*)(w + off);
    off += n * sizeof(_Float16);
    return p;
  };
  const size_t HS = (size_t)kB * kH;  // 65536
  _Float16* WAh = a16((size_t)4 * kH * (kI + kH));   // [4096][1280]
  _Float16* WAl = a16((size_t)4 * kH * (kI + kH));
  _Float16* WBh = a16((size_t)4 * kH * (2 * kH));    // [4096][2048]
  _Float16* WBl = a16((size_t)4 * kH * (2 * kH));
  _Float16* XSh = a16((size_t)kT * kB * kI);
  _Float16* XSl = a16((size_t)kT * kB * kI);
  _Float16* hA  = a16(4 * HS);  // [2 ping][hi,lo][64*1024]
  _Float16* hB  = a16(4 * HS);
  float* cA = (float*)(w + off); off += HS * sizeof(float);
  float* cB = (float*)(w + off); off += HS * sizeof(float);
  float* h2f = (float*)(w + off); off += HS * sizeof(float);
  // total ~90 MB — assumed <= ws_size

  // zero recurrent state (hA, hB, cA, cB are contiguous)
  hipMemsetAsync(hA, 0, 8 * HS * sizeof(_Float16) + 2 * HS * sizeof(float),
                 stream);

  prep_wsplit<<<1024, 256, 0, stream>>>(Wih0, kI, Whh0, kH, WAh, WAl,
                                        4 * kH * (kI + kH));
  prep_wsplit<<<1024, 256, 0, stream>>>(Wih1, kH, Whh1, kH, WBh, WBl,
                                        4 * kH * (2 * kH));
  prep_xsplit<<<1024, 256, 0, stream>>>(x, XSh, XSl);

  for (int s = 0; s <= kT; ++s) {
    lstm_step<<<256, 256, 0, stream>>>(s, WAh, WAl, WBh, WBl, XSh, XSl, hA, hB,
                                       b0, b1, cA, cB, h2f);
  }
  fc_kernel<<<kNC / 4, 256, 0, stream>>>(h2f, Wfc, bfc, out);
}

// Round 4
// 15908.232 us; speedup vs baseline: 2.4507x; 1.1067x over previous
//
#include <hip/hip_runtime.h>
#include <cmath>

typedef _Float16 f16x8 __attribute__((ext_vector_type(8)));
typedef float f32x4 __attribute__((ext_vector_type(4)));

namespace {

constexpr int kB = 64;     // batch
constexpr int kT = 512;    // time steps
constexpr int kI = 256;    // input size
constexpr int kH = 1024;   // hidden
constexpr int kNC = 1000;  // classes
constexpr int kKc = 128;   // K chunk per stage iteration
constexpr int kLP = kKc + 8;  // LDS row pitch in f16

__device__ __forceinline__ float sigmoidf_(float x) {
  return 1.0f / (1.0f + expf(-x));
}

__device__ __forceinline__ f16x8 ldh8(const _Float16* p) {
  return *reinterpret_cast<const f16x8*>(p);
}

__device__ __forceinline__ float dot4_(float4 a, float4 b) {
  return a.x * b.x + a.y * b.y + a.z * b.z + a.w * b.w;
}

// One LSTM layer step, 4 hidden units x 64 batches, split-f16 MFMA (3-product).
// 8 waves: wave = kh*4 + nw; kh = K-half, nw = batch-16 tile.
// MFMA 16x16x32_f16: A lane l holds A[l&15][(l>>4)*8+j]; B lane l holds
// B[(l>>4)*8+j][l&15]; C/D col=l&15, row=(l>>4)*4+reg (m89) -> lane-local
// epilogue: lane q=(l>>4) holds gates i,f,g,o of unit u0+q, batch nw*16+(l&15).
__device__ void lstm_phase_mfma(
    int tid, int u0, int Khalf, int len0,
    const _Float16* __restrict__ Whi, const _Float16* __restrict__ Wlo,
    const _Float16* __restrict__ in0h, const _Float16* __restrict__ in0l,
    const _Float16* __restrict__ in1h, const _Float16* __restrict__ in1l,
    const float* __restrict__ bias, float* __restrict__ c_st,
    _Float16* __restrict__ houth, _Float16* __restrict__ houtl,
    float* __restrict__ houtf,
    _Float16 (*Ahi)[16][kLP], _Float16 (*Alo)[16][kLP],
    float4 (*red)[64]) {
  const int lane = tid & 63;
  const int wave = tid >> 6;
  const int kh = wave >> 2;   // K-half this wave accumulates
  const int nw = wave & 3;    // batch-16 tile
  const int K = 2 * Khalf;
  const int kbase0 = kh * Khalf;
  const int nC = Khalf / kKc;

  // weight staging: threads [kh*256, kh*256+256) stage their half's chunk
  const int st = tid & 255;
  const int sr = st >> 4;          // 0..15 LDS row
  const int sk = (st & 15) * 8;    // k offset (8 f16)
  const int sgh = tid >> 8;        // staging half (== kh)
  const int grow = (sr & 3) * kH + u0 + (sr >> 2);
  const _Float16* wsrc_h = Whi + (size_t)grow * K + (size_t)sgh * Khalf + sk;
  const _Float16* wsrc_l = Wlo + (size_t)grow * K + (size_t)sgh * Khalf + sk;

  // compute map
  const int kg = (lane >> 4) * 8;
  const int am = lane & 15;
  const int b = nw * 16 + (lane & 15);

  f32x4 acc = {0.f, 0.f, 0.f, 0.f};

  auto baddr = [&](int gk, const _Float16*& ph, const _Float16*& pl) {
    if (gk < len0) {
      ph = in0h + (size_t)b * len0 + gk;
      pl = in0l + (size_t)b * len0 + gk;
    } else {
      ph = in1h + (size_t)b * kH + (gk - len0);
      pl = in1l + (size_t)b * kH + (gk - len0);
    }
  };

  // W prefetch depth 2 (LLC latency), B prefetch depth 1 (L2-hot)
  f16x8 wh0 = ldh8(wsrc_h);
  f16x8 wl0 = ldh8(wsrc_l);
  f16x8 wh1 = ldh8(wsrc_h + kKc);
  f16x8 wl1 = ldh8(wsrc_l + kKc);

  f16x8 bhv[4], blv[4];
#pragma unroll
  for (int ks = 0; ks < 4; ++ks) {
    const _Float16 *ph, *pl;
    baddr(kbase0 + ks * 32 + kg, ph, pl);
    bhv[ks] = ldh8(ph);
    blv[ks] = ldh8(pl);
  }

  for (int c = 0; c < nC; ++c) {
    __syncthreads();  // previous chunk's compute done; LDS free
    *reinterpret_cast<f16x8*>(&Ahi[sgh][sr][sk]) = wh0;
    *reinterpret_cast<f16x8*>(&Alo[sgh][sr][sk]) = wl0;
    wh0 = wh1;
    wl0 = wl1;
    const int cw = (c + 2 < nC) ? (c + 2) : (nC - 1);
    wh1 = ldh8(wsrc_h + (size_t)cw * kKc);
    wl1 = ldh8(wsrc_l + (size_t)cw * kKc);
    __syncthreads();  // staged chunk visible
    f16x8 nbh[4], nbl[4];
    const int cb = (c + 1 < nC) ? (c + 1) : (nC - 1);
#pragma unroll
    for (int ks = 0; ks < 4; ++ks) {
      const _Float16 *ph, *pl;
      baddr(kbase0 + cb * kKc + ks * 32 + kg, ph, pl);
      nbh[ks] = ldh8(ph);
      nbl[ks] = ldh8(pl);
    }
#pragma unroll
    for (int ks = 0; ks < 4; ++ks) {
      f16x8 ah = ldh8(&Ahi[kh][am][ks * 32 + kg]);
      f16x8 al = ldh8(&Alo[kh][am][ks * 32 + kg]);
      acc = __builtin_amdgcn_mfma_f32_16x16x32_f16(ah, bhv[ks], acc, 0, 0, 0);
      acc = __builtin_amdgcn_mfma_f32_16x16x32_f16(ah, blv[ks], acc, 0, 0, 0);
      acc = __builtin_amdgcn_mfma_f32_16x16x32_f16(al, bhv[ks], acc, 0, 0, 0);
    }
#pragma unroll
    for (int ks = 0; ks < 4; ++ks) {
      bhv[ks] = nbh[ks];
      blv[ks] = nbl[ks];
    }
  }

  // K-half reduction + lane-local cell update (barriers kept wave-uniform)
  if (kh == 1) {
    red[nw][lane] = make_float4(acc[0], acc[1], acc[2], acc[3]);
  }
  __syncthreads();
  if (kh == 0) {
    const float4 p = red[nw][lane];
    const int eb = nw * 16 + (lane & 15);
    const int eu = u0 + (lane >> 4);
    const size_t idx = (size_t)eb * kH + eu;
    const float gi = sigmoidf_(acc[0] + p.x + bias[eu]);
    const float gf = sigmoidf_(acc[1] + p.y + bias[kH + eu]);
    const float gg = tanhf(acc[2] + p.z + bias[2 * kH + eu]);
    const float go = sigmoidf_(acc[3] + p.w + bias[3 * kH + eu]);
    const float cn = gf * c_st[idx] + gi * gg;
    c_st[idx] = cn;
    const float h = go * tanhf(cn);
    const _Float16 hh = (_Float16)h;
    houth[idx] = hh;
    houtl[idx] = (_Float16)(h - (float)hh);
    if (houtf) houtf[idx] = h;
  }
}

// Superstep s: layer A computes hA[s] (if s<T), layer B computes hB[s-1] (if s>=1).
__global__ __launch_bounds__(512, 2) void lstm_step(
    int s,
    const _Float16* __restrict__ WAh, const _Float16* __restrict__ WAl,
    const _Float16* __restrict__ WBh, const _Float16* __restrict__ WBl,
    const _Float16* __restrict__ XSh, const _Float16* __restrict__ XSl,
    _Float16* __restrict__ hA, _Float16* __restrict__ hB,
    const float* __restrict__ b0v, const float* __restrict__ b1v,
    float* __restrict__ cA, float* __restrict__ cB,
    float* __restrict__ h2f) {
  __shared__ _Float16 Ahi[2][16][kLP];
  __shared__ _Float16 Alo[2][16][kLP];
  __shared__ float4 red[4][64];
  const int tid = threadIdx.x;
  const int u0 = blockIdx.x * 4;
  const int HS = kB * kH;
  const int pPrev = (s + 1) & 1, pCur = s & 1;

  _Float16* hAprevH = hA + (size_t)pPrev * 2 * HS;
  _Float16* hAprevL = hAprevH + HS;
  _Float16* hAcurH = hA + (size_t)pCur * 2 * HS;
  _Float16* hAcurL = hAcurH + HS;
  _Float16* hBprevH = hB + (size_t)pCur * 2 * HS;  // hB[s-2]: (s-2)&1 == s&1
  _Float16* hBprevL = hBprevH + HS;
  _Float16* hBcurH = hB + (size_t)pPrev * 2 * HS;  // hB[s-1]
  _Float16* hBcurL = hBcurH + HS;

  if (s < kT) {
    lstm_phase_mfma(tid, u0, (kI + kH) / 2, kI, WAh, WAl,
                    XSh + (size_t)s * kB * kI, XSl + (size_t)s * kB * kI,
                    hAprevH, hAprevL, b0v, cA, hAcurH, hAcurL, nullptr, Ahi,
                    Alo, red);
  }
  __syncthreads();
  if (s >= 1) {
    lstm_phase_mfma(tid, u0, kH, kH, WBh, WBl, hAprevH, hAprevL, hBprevH,
                    hBprevL, b1v, cB, hBcurH, hBcurL, h2f, Ahi, Alo, red);
  }
}

// Split fp32 weights [4096][k0len | k1len] into concatenated f16 hi/lo [4096][K].
__global__ __launch_bounds__(256) void prep_wsplit(
    const float* __restrict__ W0, int k0len, const float* __restrict__ W1,
    int k1len, _Float16* __restrict__ oh, _Float16* __restrict__ ol,
    int total) {
  const int K = k0len + k1len;
  for (int i = blockIdx.x * blockDim.x + threadIdx.x; i < total;
       i += gridDim.x * blockDim.x) {
    const int row = i / K, k = i % K;
    const float v = (k < k0len) ? W0[(size_t)row * k0len + k]
                                : W1[(size_t)row * k1len + (k - k0len)];
    const _Float16 h = (_Float16)v;
    oh[i] = h;
    ol[i] = (_Float16)(v - (float)h);
  }
}

// x [b][t][k] fp32 -> xs hi/lo [t][b][k] f16
__global__ __launch_bounds__(256) void prep_xsplit(
    const float* __restrict__ x, _Float16* __restrict__ oh,
    _Float16* __restrict__ ol) {
  const int total = kT * kB * kI;
  for (int i = blockIdx.x * blockDim.x + threadIdx.x; i < total;
       i += gridDim.x * blockDim.x) {
    const int k = i % kI;
    const int rem = i / kI;
    const int bb = rem % kB;
    const int t = rem / kB;
    const float v = x[((size_t)bb * kT + t) * kI + k];
    const _Float16 h = (_Float16)v;
    oh[i] = h;
    ol[i] = (_Float16)(v - (float)h);
  }
}

__global__ __launch_bounds__(256) void fc_kernel(
    const float* __restrict__ h, const float* __restrict__ Wfc,
    const float* __restrict__ bfc, float* __restrict__ out) {
  __shared__ float in_lds[kB][132];
  const int tid = threadIdx.x;
  const int cls = blockIdx.x * 4 + (tid & 3);
  const int b = tid >> 2;
  float acc = bfc[cls];
  for (int c = 0; c < kH / 128; ++c) {
    {
      const int sb = tid >> 2, sc = tid & 3;
#pragma unroll
      for (int j = 0; j < 8; ++j) {
        const int kk = (sc + j * 4) * 4;
        *reinterpret_cast<float4*>(&in_lds[sb][kk]) =
            *reinterpret_cast<const float4*>(h + (size_t)sb * kH + c * 128 + kk);
      }
    }
    __syncthreads();
    const float* wrow = Wfc + (size_t)cls * kH + c * 128;
#pragma unroll
    for (int k = 0; k < 128; k += 4) {
      float4 w = *reinterpret_cast<const float4*>(wrow + k);
      float4 v = *reinterpret_cast<const float4*>(&in_lds[b][k]);
      acc += dot4_(w, v);
    }
    __syncthreads();
  }
  out[(size_t)b * kNC + cls] = fmaxf(acc, 0.0f);
}

}  // namespace

extern "C" void kernel_launch(void* const* d_in, const int* in_sizes, int n_in,
                              void* d_out, int out_size, void* d_ws, size_t ws_size,
                              hipStream_t stream) {
  const float* x    = (const float*)d_in[0];
  const float* Wih0 = (const float*)d_in[1];
  const float* Whh0 = (const float*)d_in[2];
  const float* b0   = (const float*)d_in[3];
  const float* Wih1 = (const float*)d_in[4];
  const float* Whh1 = (const float*)d_in[5];
  const float* b1   = (const float*)d_in[6];
  const float* Wfc  = (const float*)d_in[7];
  const float* bfc  = (const float*)d_in[8];
  float* out = (float*)d_out;

  char* w = (char*)d_ws;
  size_t off = 0;
  auto a16 = [&](size_t n) {
    _Float16* p = (_Float16*)(w + off);
    off += n * sizeof(_Float16);
    return p;
  };
  const size_t HS = (size_t)kB * kH;  // 65536
  _Float16* WAh = a16((size_t)4 * kH * (kI + kH));   // [4096][1280]
  _Float16* WAl = a16((size_t)4 * kH * (kI + kH));
  _Float16* WBh = a16((size_t)4 * kH * (2 * kH));    // [4096][2048]
  _Float16* WBl = a16((size_t)4 * kH * (2 * kH));
  _Float16* XSh = a16((size_t)kT * kB * kI);
  _Float16* XSl = a16((size_t)kT * kB * kI);
  _Float16* hA  = a16(4 * HS);  // [2 ping][hi,lo][64*1024]
  _Float16* hB  = a16(4 * HS);
  float* cA = (float*)(w + off); off += HS * sizeof(float);
  float* cB = (float*)(w + off); off += HS * sizeof(float);
  float* h2f = (float*)(w + off); off += HS * sizeof(float);

  // zero recurrent state (hA, hB, cA, cB contiguous)
  hipMemsetAsync(hA, 0, 8 * HS * sizeof(_Float16) + 2 * HS * sizeof(float),
                 stream);

  prep_wsplit<<<1024, 256, 0, stream>>>(Wih0, kI, Whh0, kH, WAh, WAl,
                                        4 * kH * (kI + kH));
  prep_wsplit<<<1024, 256, 0, stream>>>(Wih1, kH, Whh1, kH, WBh, WBl,
                                        4 * kH * (2 * kH));
  prep_xsplit<<<1024, 256, 0, stream>>>(x, XSh, XSl);

  for (int s = 0; s <= kT; ++s) {
    lstm_step<<<256, 512, 0, stream>>>(s, WAh, WAl, WBh, WBl, XSh, XSl, hA, hB,
                                       b0, b1, cA, cB, h2f);
  }
  fc_kernel<<<kNC / 4, 256, 0, stream>>>(h2f, Wfc, bfc, out);
}